// Round 4
// baseline (229.446 us; speedup 1.0000x reference)
//
#include <hip/hip_runtime.h>
#include <math.h>

#define LSEQ 512
#define NA 20
#define NCH 8
#define WPAD 516      // padded Wf row stride: 516%32==4 -> conflict-free (c,s) reads
#define NBLK_IMP 129  // 129*4 = 516 >= 512 impulse waves

// ---------------------------------------------------------------------------
// wf_vt_kernel: blocks 0..128 compute impulse responses Wf[c][s] = pyramid(e_s)[c],
// 4 impulses per block (one per wave, private LDS slices — verified R0/R1 pyramid
// code). Block 129 computes vtn (uniform branch, returns before any barrier).
// ---------------------------------------------------------------------------
__global__ __launch_bounds__(256) void wf_vt_kernel(
    const float* __restrict__ w0,   // [8*3]
    const float* __restrict__ wsg,  // [8*8*8*3]
    const float* __restrict__ lpm,
    const float* __restrict__ pm,
    float* __restrict__ wf,         // [8*WPAD]
    float* __restrict__ vtn)        // [400]
{
    if (blockIdx.x == NBLK_IMP) {
        // R3 bug was here: only threadIdx.x<256 wrote, leaving vtn[256..399]
        // poisoned. Grid-stride loop covers all 400 entries.
        for (int o = threadIdx.x; o < NA * NA; o += 256) {
            int j = o / NA, a = o % NA;
            float v = 0.f;
            if (a > j && a <= NA - 2)
                v += fminf(fmaxf(lpm[j * NA + a], 0.001f), 1.0f) * pm[j * NA + a];
            if (a < j)
                v += fminf(fmaxf(lpm[a * NA + j], 0.001f), 1.0f) * pm[a * NA + j];
            vtn[o] = v;
        }
        return;
    }

    const int w = threadIdx.x >> 6;   // wave 0..3 -> impulse index
    const int t = threadIdx.x & 63;   // lane
    const int s = blockIdx.x * 4 + w; // impulse position (>=512: compute on zeros, skip write)

    __shared__ float s_h[4][LSEQ];
    __shared__ float s_a[4][NCH * 256];
    __shared__ float s_b[4][NCH * 128];
    float* hh = s_h[w];
    float* aa = s_a[w];
    float* bb = s_b[w];

    for (int i = t; i < LSEQ; i += 64) hh[i] = (i == s) ? 1.f : 0.f;
    __syncthreads();

    const int c = t >> 3;
    const int pb = t & 7;

    // layer 0: 1 -> 8 channels, 512 -> 256
    {
        float q0 = w0[c * 3 + 0], q1 = w0[c * 3 + 1], q2 = w0[c * 3 + 2];
        float wa = q0, wb = q0 + q1, wc2 = q1 + q2, wd = q2;
        for (int p = pb; p < 256; p += 8) {
            int xx = 2 * p;
            float x0 = (xx > 0) ? hh[xx - 1] : 0.f;
            float x1 = hh[xx];
            float x2 = hh[xx + 1];
            float x3 = (xx + 2 < LSEQ) ? hh[xx + 2] : 0.f;
            aa[c * 256 + p] = 0.5f * (wa * x0 + wb * x1 + wc2 * x2 + wd * x3);
        }
    }
    __syncthreads();

    int Lin = 256;
    for (int li = 0; li < 8; ++li) {
        const float* fin = (li & 1) ? bb : aa;
        float* fout = (li & 1) ? aa : bb;
        const int Lout = Lin >> 1;

        float wa[8], wb[8], wc2[8], wd[8];
        const float* wl = wsg + li * 192 + c * 24;
#pragma unroll
        for (int ci = 0; ci < 8; ++ci) {
            float q0 = wl[ci * 3 + 0], q1 = wl[ci * 3 + 1], q2 = wl[ci * 3 + 2];
            wa[ci] = q0; wb[ci] = q0 + q1; wc2[ci] = q1 + q2; wd[ci] = q2;
        }

        for (int p = pb; p < Lout; p += 8) {
            int xx = 2 * p;
            float acc = 0.f;
#pragma unroll
            for (int ci = 0; ci < 8; ++ci) {
                const float* ip = fin + ci * Lin + xx;
                float x0 = (xx > 0) ? ip[-1] : 0.f;
                float x1 = ip[0];
                float x2 = ip[1];
                float x3 = (xx + 2 < Lin) ? ip[2] : 0.f;
                acc += wa[ci] * x0 + wb[ci] * x1 + wc2[ci] * x2 + wd[ci] * x3;
            }
            fout[c * Lout + p] = 0.5f * acc;
        }
        __syncthreads();
        Lin = Lout;
    }

    if (t < NCH && s < LSEQ) wf[t * WPAD + s] = aa[t];
}

// ---------------------------------------------------------------------------
// main_kernel: one block per b.
//  phase 0: zero per-wave G/R accumulators; stage Wf (16.5KB) + vtn; idx from x
//  phase 1: scatter pass — lane (c,so) over wave's 128-s range:
//           G[w][j][c]  += Wf[c,s]              (j = idx_s, valid only)
//           R[w][a][c]  += vk * Wf[c,s]         (deduped neighbor candidates,
//                                                k=3>2>1 priority, boundary folds)
//  phase 2: out[a,c] = G[a][c] + R[a][c] + sum_j vtn[j][a]*G[j][c]
// ---------------------------------------------------------------------------
__global__ __launch_bounds__(256) void main_kernel(
    const float* __restrict__ x,      // [B,L,A]
    const float* __restrict__ vtn,    // [400]
    const float* __restrict__ g_std,  // [1]
    const float* __restrict__ wf,     // [8*WPAD]
    float* __restrict__ out)          // [B*160]
{
    const int b = blockIdx.x;
    const int t = threadIdx.x;
    const int w = t >> 6;
    const int lane = t & 63;
    const int c = lane >> 3;
    const int so = lane & 7;

    __shared__ __align__(16) float s_w[NCH * WPAD];  // 16512B
    __shared__ __align__(16) float s_vtn[NA * NA];   // 1600B
    __shared__ float s_G[4 * NA * NCH];              // 2560B
    __shared__ float s_R[4 * NA * NCH];              // 2560B
    __shared__ float s_Gs[NA * NCH];                 // 640B
    __shared__ unsigned char s_idx[LSEQ];            // 512B

    // ---- phase 0 ----
    for (int e = t; e < 4 * NA * NCH; e += 256) { s_G[e] = 0.f; s_R[e] = 0.f; }

    float4* s_w4 = (float4*)s_w;
    const float4* g_w4 = (const float4*)wf;
    for (int e = t; e < NCH * WPAD / 4; e += 256) s_w4[e] = g_w4[e];
    if (t < NA * NA / 4) ((float4*)s_vtn)[t] = ((const float4*)vtn)[t];

    const float4* xb = (const float4*)(x + (size_t)b * LSEQ * NA);
#pragma unroll
    for (int rep = 0; rep < 2; ++rep) {
        int s = t + rep * 256;
        int id = 255;
#pragma unroll
        for (int q = 0; q < 5; ++q) {
            float4 v = xb[s * 5 + q];
            if (v.x > .5f) id = 4 * q + 0;
            if (v.y > .5f) id = 4 * q + 1;
            if (v.z > .5f) id = 4 * q + 2;
            if (v.w > .5f) id = 4 * q + 3;
        }
        s_idx[s] = (unsigned char)id;
    }
    __syncthreads();

    const float stdv = g_std[0];
    const float inv2s2 = 1.f / (2.f * stdv * stdv);
    const float v1 = __expf(-1.f * inv2s2);
    const float v2 = __expf(-4.f * inv2s2);
    const float v3 = __expf(-9.f * inv2s2);

    // ---- phase 1: scatter ----
    float* Gp = s_G + w * (NA * NCH);
    float* Rp = s_R + w * (NA * NCH);
#pragma unroll 1
    for (int it = 0; it < 16; ++it) {
        const int s = w * 128 + it * 8 + so;
        const float wv = s_w[c * WPAD + s];
        const int j = s_idx[s];
        if (j < NA) atomicAdd(&Gp[j * NCH + c], wv);

        if (s == 0 || s == LSEQ - 1) {
            // boundary fold: candidates idx[0..3] (s=0) / idx[508..511] (s=511), all v3
            const int base = (s == 0) ? 0 : LSEQ - 4;
            const int u0 = s_idx[base + 0], u1 = s_idx[base + 1];
            const int u2 = s_idx[base + 2], u3 = s_idx[base + 3];
            const float a3 = v3 * wv;
            if (u0 < NA) atomicAdd(&Rp[u0 * NCH + c], a3);
            if (u1 < NA && u1 != u0) atomicAdd(&Rp[u1 * NCH + c], a3);
            if (u2 < NA && u2 != u0 && u2 != u1) atomicAdd(&Rp[u2 * NCH + c], a3);
            if (u3 < NA && u3 != u0 && u3 != u1 && u3 != u2) atomicAdd(&Rp[u3 * NCH + c], a3);
        } else {
            const int tp3 = (s >= 3) ? s_idx[s - 3] : 255;
            const int tn3 = (s + 3 <= LSEQ - 1) ? s_idx[s + 3] : 255;
            const int tp2 = (s >= 2) ? s_idx[s - 2] : 255;
            const int tn2 = (s + 2 <= LSEQ - 1) ? s_idx[s + 2] : 255;
            const int tp1 = s_idx[s - 1];
            const int tn1 = s_idx[s + 1];
            if (tp3 < NA) atomicAdd(&Rp[tp3 * NCH + c], v3 * wv);
            if (tn3 < NA && tn3 != tp3) atomicAdd(&Rp[tn3 * NCH + c], v3 * wv);
            if (tp2 < NA && tp2 != tp3 && tp2 != tn3)
                atomicAdd(&Rp[tp2 * NCH + c], v2 * wv);
            if (tn2 < NA && tn2 != tp3 && tn2 != tn3 && tn2 != tp2)
                atomicAdd(&Rp[tn2 * NCH + c], v2 * wv);
            if (tp1 < NA && tp1 != tp3 && tp1 != tn3 && tp1 != tp2 && tp1 != tn2)
                atomicAdd(&Rp[tp1 * NCH + c], v1 * wv);
            if (tn1 < NA && tn1 != tp3 && tn1 != tn3 && tn1 != tp2 && tn1 != tn2 && tn1 != tp1)
                atomicAdd(&Rp[tn1 * NCH + c], v1 * wv);
        }
    }
    __syncthreads();

    // ---- phase 2: reduce + combine ----
    if (t < NA * NCH)
        s_Gs[t] = s_G[t] + s_G[160 + t] + s_G[320 + t] + s_G[480 + t];
    __syncthreads();

    if (t < NA * NCH) {
        const int a = t >> 3, cc = t & 7;
        float acc = s_Gs[t] + s_R[t] + s_R[160 + t] + s_R[320 + t] + s_R[480 + t];
#pragma unroll
        for (int j = 0; j < NA; ++j)
            acc += s_vtn[j * NA + a] * s_Gs[j * NCH + cc];
        out[(size_t)b * (NA * NCH) + t] = acc;
    }
}

extern "C" void kernel_launch(void* const* d_in, const int* in_sizes, int n_in,
                              void* d_out, int out_size, void* d_ws, size_t ws_size,
                              hipStream_t stream) {
    const float* x    = (const float*)d_in[0];
    // d_in[1] = masks (bool) — unused; mask derived from x
    const float* lpm  = (const float*)d_in[2];
    const float* pm   = (const float*)d_in[3];
    const float* stdp = (const float*)d_in[4];
    const float* w0   = (const float*)d_in[5];
    const float* wsg  = (const float*)d_in[6];
    float* out = (float*)d_out;

    const int B = in_sizes[0] / (LSEQ * NA);  // 1024

    float* vtn = (float*)d_ws;                 // 400 floats (pad to 1024)
    float* wfb = (float*)d_ws + 1024;          // 8*WPAD floats

    wf_vt_kernel<<<dim3(NBLK_IMP + 1), dim3(256), 0, stream>>>(w0, wsg, lpm, pm, wfb, vtn);
    main_kernel<<<dim3(B), dim3(256), 0, stream>>>(x, vtn, stdp, wfb, out);
}

// Round 5
// 124.678 us; speedup vs baseline: 1.8403x; 1.8403x over previous
//
#include <hip/hip_runtime.h>
#include <math.h>

#define LSEQ 512
#define NA 20
#define NCH 8
#define NBLK_IMP 129  // 129*4 = 516 >= 512 impulse waves

// ---------------------------------------------------------------------------
// wf_vt_kernel: blocks 0..128 compute impulse responses Wf[c][s] = pyramid(e_s)[c],
// 4 impulses per block (one per wave, private LDS slices — verified R0/R1/R4
// pyramid code). Block 129 computes vtn (grid-stride over all 400 entries).
// wf layout: [c][s], stride 512.
// ---------------------------------------------------------------------------
__global__ __launch_bounds__(256) void wf_vt_kernel(
    const float* __restrict__ w0,   // [8*3]
    const float* __restrict__ wsg,  // [8*8*8*3]
    const float* __restrict__ lpm,
    const float* __restrict__ pm,
    float* __restrict__ wf,         // [8*512]
    float* __restrict__ vtn)        // [400]
{
    if (blockIdx.x == NBLK_IMP) {
        for (int o = threadIdx.x; o < NA * NA; o += 256) {
            int j = o / NA, a = o % NA;
            float v = 0.f;
            if (a > j && a <= NA - 2)
                v += fminf(fmaxf(lpm[j * NA + a], 0.001f), 1.0f) * pm[j * NA + a];
            if (a < j)
                v += fminf(fmaxf(lpm[a * NA + j], 0.001f), 1.0f) * pm[a * NA + j];
            vtn[o] = v;
        }
        return;
    }

    const int w = threadIdx.x >> 6;   // wave 0..3 -> impulse index
    const int t = threadIdx.x & 63;   // lane
    const int s = blockIdx.x * 4 + w; // impulse position (>=512: compute on zeros, skip write)

    __shared__ float s_h[4][LSEQ];
    __shared__ float s_a[4][NCH * 256];
    __shared__ float s_b[4][NCH * 128];
    float* hh = s_h[w];
    float* aa = s_a[w];
    float* bb = s_b[w];

    for (int i = t; i < LSEQ; i += 64) hh[i] = (i == s) ? 1.f : 0.f;
    __syncthreads();

    const int c = t >> 3;
    const int pb = t & 7;

    // layer 0: 1 -> 8 channels, 512 -> 256
    {
        float q0 = w0[c * 3 + 0], q1 = w0[c * 3 + 1], q2 = w0[c * 3 + 2];
        float wa = q0, wb = q0 + q1, wc2 = q1 + q2, wd = q2;
        for (int p = pb; p < 256; p += 8) {
            int xx = 2 * p;
            float x0 = (xx > 0) ? hh[xx - 1] : 0.f;
            float x1 = hh[xx];
            float x2 = hh[xx + 1];
            float x3 = (xx + 2 < LSEQ) ? hh[xx + 2] : 0.f;
            aa[c * 256 + p] = 0.5f * (wa * x0 + wb * x1 + wc2 * x2 + wd * x3);
        }
    }
    __syncthreads();

    int Lin = 256;
    for (int li = 0; li < 8; ++li) {
        const float* fin = (li & 1) ? bb : aa;
        float* fout = (li & 1) ? aa : bb;
        const int Lout = Lin >> 1;

        float wa[8], wb[8], wc2[8], wd[8];
        const float* wl = wsg + li * 192 + c * 24;
#pragma unroll
        for (int ci = 0; ci < 8; ++ci) {
            float q0 = wl[ci * 3 + 0], q1 = wl[ci * 3 + 1], q2 = wl[ci * 3 + 2];
            wa[ci] = q0; wb[ci] = q0 + q1; wc2[ci] = q1 + q2; wd[ci] = q2;
        }

        for (int p = pb; p < Lout; p += 8) {
            int xx = 2 * p;
            float acc = 0.f;
#pragma unroll
            for (int ci = 0; ci < 8; ++ci) {
                const float* ip = fin + ci * Lin + xx;
                float x0 = (xx > 0) ? ip[-1] : 0.f;
                float x1 = ip[0];
                float x2 = ip[1];
                float x3 = (xx + 2 < Lin) ? ip[2] : 0.f;
                acc += wa[ci] * x0 + wb[ci] * x1 + wc2[ci] * x2 + wd[ci] * x3;
            }
            fout[c * Lout + p] = 0.5f * acc;
        }
        __syncthreads();
        Lin = Lout;
    }

    if (t < NCH && s < LSEQ) wf[t * 512 + s] = aa[t];
}

// ---------------------------------------------------------------------------
// main_kernel: one block per b.  No LDS atomics anywhere.
//  phase 0: load Wf strips into registers (thread (c,seg) owns positions
//           seg*4+128k+i); stage vtn; idx from global x (coalesced b128)
//  phase 1: dense h build (R2-verified): h[a][s] for all 20 a, row-scatter
//           within own column s only (k=1,2,3 write order -> k=3 priority)
//  phase 2: out[a,c] = dot(h[a], Wf[c]): per a, 4 conflict-free b128 reads
//           (seg*4 strips tile all 32 banks), 16 fma, shfl seg-reduce
// ---------------------------------------------------------------------------
__global__ __launch_bounds__(256) void main_kernel(
    const float* __restrict__ x,      // [B,L,A]
    const float* __restrict__ vtn,    // [400]
    const float* __restrict__ g_std,  // [1]
    const float* __restrict__ wf,     // [8*512]
    float* __restrict__ out)          // [B*160]
{
    const int b = blockIdx.x;
    const int t = threadIdx.x;
    const int c = t & 7;       // channel
    const int seg = t >> 3;    // 0..31: owns s = seg*4 + 128k + i
    const int w = t >> 6;
    const int lane = t & 63;

    __shared__ __align__(16) float s_h[NA * 512];   // 40960B
    __shared__ __align__(16) float s_vtn[NA * NA];  // 1600B
    __shared__ float s_part[4 * NA * NCH];          // 2560B
    __shared__ unsigned char s_idx[LSEQ];           // 512B

    // ---- phase 0: weights -> registers, vtn -> LDS, idx from global ----
    float4 wr[4];
#pragma unroll
    for (int k = 0; k < 4; ++k)
        wr[k] = *(const float4*)(wf + c * 512 + seg * 4 + 128 * k);

    if (t < NA * NA / 4) ((float4*)s_vtn)[t] = ((const float4*)vtn)[t];

    const float4* xb = (const float4*)(x + (size_t)b * LSEQ * NA);
#pragma unroll
    for (int rep = 0; rep < 2; ++rep) {
        int s = t + rep * 256;
        int id = 255;
#pragma unroll
        for (int q = 0; q < 5; ++q) {
            float4 v = xb[s * 5 + q];
            if (v.x > .5f) id = 4 * q + 0;
            if (v.y > .5f) id = 4 * q + 1;
            if (v.z > .5f) id = 4 * q + 2;
            if (v.w > .5f) id = 4 * q + 3;
        }
        s_idx[s] = (unsigned char)id;
    }
    __syncthreads();

    const float stdv = g_std[0];
    const float inv2s2 = 1.f / (2.f * stdv * stdv);
    const float vks[3] = {__expf(-1.f * inv2s2), __expf(-4.f * inv2s2), __expf(-9.f * inv2s2)};

    // ---- phase 1: dense h build (each lane writes only its own column s) ----
    for (int s = t; s < LSEQ; s += 256) {
        const int ai = s_idx[s];
        const bool valid = ai < NA;
#pragma unroll
        for (int a = 0; a < NA; ++a) {
            float v = valid ? (s_vtn[ai * NA + a] + (a == ai ? 1.f : 0.f)) : 0.f;
            s_h[a * 512 + s] = v;
        }
#pragma unroll
        for (int k = 1; k <= 3; ++k) {
            const float add = vks[k - 1];
            if (s == LSEQ - 1) {
                for (int u = LSEQ - 1 - k; u <= LSEQ - 1; ++u) {
                    int tg = s_idx[u];
                    if (tg < NA)
                        s_h[tg * 512 + s] =
                            (valid ? s_vtn[ai * NA + tg] + (tg == ai ? 1.f : 0.f) : 0.f) + add;
                }
            } else if (s >= k) {
                int tg = s_idx[s - k];
                if (tg < NA)
                    s_h[tg * 512 + s] =
                        (valid ? s_vtn[ai * NA + tg] + (tg == ai ? 1.f : 0.f) : 0.f) + add;
            }
            if (s == 0) {
                for (int u = 0; u <= k; ++u) {
                    int tg = s_idx[u];
                    if (tg < NA)
                        s_h[tg * 512 + s] =
                            (valid ? s_vtn[ai * NA + tg] + (tg == ai ? 1.f : 0.f) : 0.f) + add;
                }
            } else if (s + k < LSEQ) {
                int tg = s_idx[s + k];
                if (tg < NA)
                    s_h[tg * 512 + s] =
                        (valid ? s_vtn[ai * NA + tg] + (tg == ai ? 1.f : 0.f) : 0.f) + add;
            }
        }
    }
    __syncthreads();

    // ---- phase 2: dots ----
#pragma unroll 1
    for (int a = 0; a < NA; ++a) {
        const float* hb = s_h + a * 512 + seg * 4;
        float acc = 0.f;
#pragma unroll
        for (int k = 0; k < 4; ++k) {
            float4 hv = *(const float4*)(hb + 128 * k);
            acc += hv.x * wr[k].x + hv.y * wr[k].y + hv.z * wr[k].z + hv.w * wr[k].w;
        }
        acc += __shfl_xor(acc, 8);
        acc += __shfl_xor(acc, 16);
        acc += __shfl_xor(acc, 32);
        if ((lane >> 3) == 0) s_part[w * (NA * NCH) + a * NCH + c] = acc;
    }
    __syncthreads();

    if (t < NA * NCH)
        out[(size_t)b * (NA * NCH) + t] =
            s_part[t] + s_part[160 + t] + s_part[320 + t] + s_part[480 + t];
}

extern "C" void kernel_launch(void* const* d_in, const int* in_sizes, int n_in,
                              void* d_out, int out_size, void* d_ws, size_t ws_size,
                              hipStream_t stream) {
    const float* x    = (const float*)d_in[0];
    // d_in[1] = masks (bool) — unused; mask derived from x
    const float* lpm  = (const float*)d_in[2];
    const float* pm   = (const float*)d_in[3];
    const float* stdp = (const float*)d_in[4];
    const float* w0   = (const float*)d_in[5];
    const float* wsg  = (const float*)d_in[6];
    float* out = (float*)d_out;

    const int B = in_sizes[0] / (LSEQ * NA);  // 1024

    float* vtn = (float*)d_ws;                 // 400 floats (pad to 1024)
    float* wfb = (float*)d_ws + 1024;          // 8*512 floats

    wf_vt_kernel<<<dim3(NBLK_IMP + 1), dim3(256), 0, stream>>>(w0, wsg, lpm, pm, wfb, vtn);
    main_kernel<<<dim3(B), dim3(256), 0, stream>>>(x, vtn, stdp, wfb, out);
}